// Round 10
// baseline (180.661 us; speedup 1.0000x reference)
//
#include <hip/hip_runtime.h>
#include <hip/hip_bf16.h>

using u16 = unsigned short;
typedef __attribute__((ext_vector_type(8))) short bf16x8;
typedef __attribute__((ext_vector_type(4))) float f32x4;

static constexpr int N  = 2;
static constexpr int C  = 64;
static constexpr int H  = 256;
static constexpr int W  = 256;
static constexpr int Hd = 128;
static constexpr int Wd = 128;
static constexpr int KK = 25;
static constexpr int C2 = 256;
static constexpr int OC = 64;
static constexpr int HWP  = H * W;    // 65536
static constexpr int HDWD = Hd * Wd;  // 16384

__device__ __forceinline__ float bflo(unsigned u) { return __uint_as_float(u << 16); }
__device__ __forceinline__ float bfhi(unsigned u) { return __uint_as_float(u & 0xffff0000u); }
__device__ __forceinline__ unsigned pack2(float a, float b) {
    __hip_bfloat16 ha = __float2bfloat16(a), hb = __float2bfloat16(b);
    union { __hip_bfloat16 h; u16 u; } ua{ha}, ub{hb};
    return (unsigned)ua.u | ((unsigned)ub.u << 16);
}
__device__ __forceinline__ u16 f2bf(float f) {
    union { __hip_bfloat16 h; u16 u; } v{__float2bfloat16(f)};
    return v.u;
}

// ---------------- Kernel A: 1x1 down conv -> k1 PIXEL-MAJOR [n][px][cm] -----
// grid(1024): 128-px tile (R6-benched shape). thread = 4 px x 8 cm.
__global__ __launch_bounds__(256) void kA_down(const float* __restrict__ x,
                                               const float* __restrict__ w,
                                               const float* __restrict__ b,
                                               u16* __restrict__ k1) {
    __shared__ u16   xt[64][128];
    __shared__ float wt[64][66];
    const int tid = threadIdx.x;
    const int pg0 = blockIdx.x * 128;
    const int n   = pg0 >> 16;
    const int px0 = pg0 & (HWP - 1);

#pragma unroll
    for (int i = 0; i < 16; ++i) {
        int e  = i * 256 + tid;
        int cm = e >> 6, c = e & 63;
        wt[c][cm] = w[e];
    }
    const float* xb = x + (size_t)n * C * HWP + px0;
#pragma unroll
    for (int i = 0; i < 8; ++i) {
        int flat = i * 256 + tid;
        int row  = flat >> 5;
        int col4 = flat & 31;
        float4 v = *(const float4*)(xb + (size_t)row * HWP + col4 * 4);
        uint2 p;
        p.x = pack2(v.x, v.y);
        p.y = pack2(v.z, v.w);
        *(uint2*)&xt[row][col4 * 4] = p;
    }
    __syncthreads();

    const int cg  = tid & 7;
    const int pxg = tid >> 3;
    float acc[8][4];
#pragma unroll
    for (int j = 0; j < 8; ++j) {
        float bj = b[cg * 8 + j];
#pragma unroll
        for (int p = 0; p < 4; ++p) acc[j][p] = bj;
    }
#pragma unroll 8
    for (int c = 0; c < 64; ++c) {
        uint2 xv = *(const uint2*)&xt[c][pxg * 4];
        float xs[4] = {bflo(xv.x), bfhi(xv.x), bflo(xv.y), bfhi(xv.y)};
        float2 w01 = *(const float2*)&wt[c][cg * 8 + 0];
        float2 w23 = *(const float2*)&wt[c][cg * 8 + 2];
        float2 w45 = *(const float2*)&wt[c][cg * 8 + 4];
        float2 w67 = *(const float2*)&wt[c][cg * 8 + 6];
        float wv[8] = {w01.x, w01.y, w23.x, w23.y, w45.x, w45.y, w67.x, w67.y};
#pragma unroll
        for (int j = 0; j < 8; ++j)
#pragma unroll
            for (int p = 0; p < 4; ++p) acc[j][p] = fmaf(wv[j], xs[p], acc[j][p]);
    }
#pragma unroll
    for (int p = 0; p < 4; ++p) {
        uint4 o;
        o.x = pack2(acc[0][p], acc[1][p]);
        o.y = pack2(acc[2][p], acc[3][p]);
        o.z = pack2(acc[4][p], acc[5][p]);
        o.w = pack2(acc[6][p], acc[7][p]);
        *(uint4*)(k1 + ((size_t)pg0 + pxg * 4 + p) * 64 + cg * 8) = o;
    }
}

// ---- Kernel W2: pack enc weights into MFMA B-fragment layout (bf16) --------
__global__ __launch_bounds__(256) void kW2_pack(const float* __restrict__ ew,
                                                u16* __restrict__ bfr) {
    int idx = blockIdx.x * 256 + threadIdx.x;   // over 36*64 = 2304
    if (idx < 2304) {
        int l  = idx & 63;
        int ft = idx >> 6;
        int t  = ft & 1, s = ft >> 1;
        int tap = s >> 1, h = s & 1;
        int c = l & 15, q = l >> 4;
        int kk = t * 16 + c;
        u16 o[8];
#pragma unroll
        for (int j = 0; j < 8; ++j) {
            int cm = 32 * h + 8 * q + j;
            float v = (kk < 25) ? ew[(kk * 64 + cm) * 9 + tap] : 0.f;
            o[j] = f2bf(v);
        }
        *(uint4*)(bfr + (size_t)idx * 8) = *(uint4*)o;
    }
}

// ---- Kernel W3: pack out-conv weights ow[co][c2] -> MFMA B-frags (bf16) ----
// bfr2[(s*4+nt)*64 + l][8]: co = nt*16 + (l&15), c2 = s*32 + (l>>4)*8 + j.
__global__ __launch_bounds__(256) void kW3_pack(const float* __restrict__ ow,
                                                u16* __restrict__ bfr2) {
    int idx = blockIdx.x * 256 + threadIdx.x;   // over 32*64 = 2048
    if (idx < 2048) {
        int l  = idx & 63;
        int ft = idx >> 6;
        int nt = ft & 3, s = ft >> 2;
        int c = l & 15, q = l >> 4;
        int co = nt * 16 + c;
        u16 o[8];
#pragma unroll
        for (int j = 0; j < 8; ++j)
            o[j] = f2bf(ow[co * 256 + s * 32 + q * 8 + j]);
        *(uint4*)(bfr2 + (size_t)idx * 8) = *(uint4*)o;
    }
}

// -------- Kernel B2: enc conv as MFMA GEMM + in-register softmax ------------
__global__ __launch_bounds__(256) void kB2_enc(const u16* __restrict__ k1,
                                               const u16* __restrict__ bfr,
                                               const float* __restrict__ eb,
                                               float* __restrict__ ksm) {
    __shared__ u16 tile[3 * 130 * 72];
    const int tid = threadIdx.x;
    const int b   = blockIdx.x;
    const int half = b & 1;
    const int hd   = (b >> 1) & 127;
    const int n    = b >> 8;
    const int w0 = half * 64;
    const int xb = 2 * w0 - 1;
    const int y0 = 2 * hd - 1;
    const u16* kb = k1 + (size_t)n * HWP * 64;

    for (int r = 0; r < 13; ++r) {
        int f = r * 256 + tid;
        if (f < 3096) {
            int p  = f >> 3, ch = f & 7;
            int y  = p / 129, xi = p - y * 129;
            int yy = y0 + y, xx = xb + xi;
            uint4 v = make_uint4(0u, 0u, 0u, 0u);
            if (yy >= 0 && xx >= 0 && xx < 256)
                v = *(const uint4*)(kb + ((size_t)(yy * W + xx)) * 64 + ch * 8);
            *(uint4*)&tile[(y * 130 + xi) * 72 + ch * 8] = v;
        }
    }
    __syncthreads();

    const int wv = tid >> 6;
    const int l  = tid & 63;
    const int c  = l & 15;
    const int q  = l >> 4;

    f32x4 acc0 = {0.f, 0.f, 0.f, 0.f};
    f32x4 acc1 = {0.f, 0.f, 0.f, 0.f};
#pragma unroll
    for (int s = 0; s < 18; ++s) {
        const int tap = s >> 1, h = s & 1;
        const int dy = tap / 3, dx = tap - dy * 3;
        const u16* ap = &tile[(dy * 130 + 32 * wv + 2 * c + dx) * 72 + 32 * h + 8 * q];
        bf16x8 a  = *(const bf16x8*)ap;
        bf16x8 b0 = *(const bf16x8*)(bfr + ((size_t)(s * 2 + 0) * 64 + l) * 8);
        bf16x8 b1 = *(const bf16x8*)(bfr + ((size_t)(s * 2 + 1) * 64 + l) * 8);
        acc0 = __builtin_amdgcn_mfma_f32_16x16x32_bf16(a, b0, acc0, 0, 0, 0);
        acc1 = __builtin_amdgcn_mfma_f32_16x16x32_bf16(a, b1, acc1, 0, 0, 0);
    }

    const float e0 = eb[c];
    const float e1 = eb[min(16 + c, 24)];
    const bool c9 = (c < 9);

#pragma unroll
    for (int r = 0; r < 4; ++r) {
        float l0 = acc0[r] + e0;
        float l1 = c9 ? (acc1[r] + e1) : -1e30f;
        float mx = fmaxf(l0, l1);
#pragma unroll
        for (int d = 1; d < 16; d <<= 1) mx = fmaxf(mx, __shfl_xor(mx, d, 64));
        float x0 = __expf(l0 - mx);
        float x1 = c9 ? __expf(l1 - mx) : 0.f;
        float sm = x0 + x1;
#pragma unroll
        for (int d = 1; d < 16; d <<= 1) sm += __shfl_xor(sm, d, 64);
        float inv = 1.f / sm;
        int wd = w0 + 16 * wv + q * 4 + r;
        float* op = ksm + (size_t)n * KK * HDWD + hd * Wd + wd;
        op[(size_t)c * HDWD] = x0 * inv;
        if (c9) op[(size_t)(16 + c) * HDWD] = x1 * inv;
    }
}

// ---- Kernel C2: reassembly -> out2 PIXEL-MAJOR [n][px][c2] -----------------
// grid(1024): b -> cc(4ch)=b&15, hdt(4hd)=(b>>4)&31, n=b>>9. All 4 q in-block
// (q-planes share the same softmax weights kw[25]!). Thread = (hdo, wd-pair).
__global__ __launch_bounds__(256) void kC2_reassemble(const float* __restrict__ x,
                                                      const float* __restrict__ ksm,
                                                      u16* __restrict__ out2p) {
    __shared__ float xts[4 * 6 * 272];   // 4 q-strips x 6 rows x 272 floats
    const int tid = threadIdx.x;
    const int b   = blockIdx.x;
    const int cc  = b & 15;
    const int hdt = (b >> 4) & 31;
    const int n   = b >> 9;
    const int hd0 = hdt * 4;
    const int hdo = tid >> 6;        // 0..3
    const int wdg = tid & 63;        // 0..63
    const int hd  = hd0 + hdo;
    const int wd0 = wdg * 2;
    const int w0  = ((hdo & 1) << 7) + wd0;
    const int lr0 = hdo >> 1;
    const int c0  = cc * 4;

    // softmax weights once (shared by all q!)
    const float* kb = ksm + (size_t)n * KK * HDWD + hd * Wd + wd0;
    float2 kw[25];
#pragma unroll
    for (int kk = 0; kk < 25; ++kk) kw[kk] = *(const float2*)(kb + (size_t)kk * HDWD);

    // staging descriptors: 1632 float4 slots = 4 strips x 6 rows x 68 slots
    int  soff[7];
    bool sval[7];
#pragma unroll
    for (int k = 0; k < 7; ++k) {
        int s = tid + 256 * k;
        int strip = s / 408;
        int rem   = s - 408 * strip;
        int r     = rem / 68;
        int c4    = rem - 68 * r;
        int y     = strip * 64 + (hd0 >> 1) - 2 + r;
        sval[k] = (s < 1632) & (c4 >= 1) & (c4 <= 64) & (y >= 0) & (y < H);
        int yc  = min(max(y, 0), H - 1);
        soff[k] = yc * W + (c4 - 1) * 4;
    }

    unsigned o0[8], o1[8];   // 16 bf16 per px (c2-local 0..15)
    const float4 z = make_float4(0.f, 0.f, 0.f, 0.f);

#pragma unroll
    for (int ci = 0; ci < 4; ++ci) {
        __syncthreads();
        const float* base = x + (size_t)(n * C + c0 + ci) * HWP;
#pragma unroll
        for (int k = 0; k < 7; ++k) {
            int s = tid + 256 * k;
            if (s < 1632) {
                float4 v = sval[k] ? *(const float4*)(base + soff[k]) : z;
                *(float4*)&xts[4 * s] = v;
            }
        }
        __syncthreads();

#pragma unroll
        for (int q = 0; q < 4; ++q) {
            float a0 = 0.f, a1 = 0.f;
#pragma unroll
            for (int i = 0; i < 5; ++i) {
                const float* rr = &xts[(q * 6 + lr0 + i) * 272 + w0 + 2];
                float2 r0 = *(const float2*)(rr + 0);
                float2 r1 = *(const float2*)(rr + 2);
                float2 r2 = *(const float2*)(rr + 4);
                float f[6] = {r0.x, r0.y, r1.x, r1.y, r2.x, r2.y};
#pragma unroll
                for (int j = 0; j < 5; ++j) {
                    const float2 kv = kw[i * 5 + j];
                    a0 = fmaf(f[j + 0], kv.x, a0);
                    a1 = fmaf(f[j + 1], kv.y, a1);
                }
            }
            const int idx  = 4 * ci + q;       // compile-time
            const int word = idx >> 1;
            if ((idx & 1) == 0) {
                o0[word] = (unsigned)f2bf(a0);
                o1[word] = (unsigned)f2bf(a1);
            } else {
                o0[word] |= ((unsigned)f2bf(a0)) << 16;
                o1[word] |= ((unsigned)f2bf(a1)) << 16;
            }
        }
    }

    // write pixel-major: 2 px x 32 B aligned chunks at c2 = 16cc..16cc+15
    u16* p0 = out2p + ((size_t)(n * HDWD + hd * Wd + wd0)) * 256 + cc * 16;
    *(uint4*)(p0 + 0) = make_uint4(o0[0], o0[1], o0[2], o0[3]);
    *(uint4*)(p0 + 8) = make_uint4(o0[4], o0[5], o0[6], o0[7]);
    u16* p1 = p0 + 256;
    *(uint4*)(p1 + 0) = make_uint4(o1[0], o1[1], o1[2], o1[3]);
    *(uint4*)(p1 + 8) = make_uint4(o1[4], o1[5], o1[6], o1[7]);
}

// ---- Kernel D2: 1x1 out conv as MFMA GEMM (no LDS) -------------------------
// grid(512): block = 64 px; wave nt = 16-co n-tile; A-frags direct from
// pixel-major out2p; B pre-packed by kW3.
__global__ __launch_bounds__(256) void kD2_out(const u16* __restrict__ out2p,
                                               const u16* __restrict__ bfr2,
                                               const float* __restrict__ ob,
                                               float* __restrict__ out) {
    const int tid = threadIdx.x;
    const int b   = blockIdx.x;
    const int px0g = b * 64;             // global flat pixel (spans n)
    const int n    = px0g >> 14;
    const int px0  = px0g & (HDWD - 1);
    const int nt = tid >> 6;
    const int l  = tid & 63;
    const int c  = l & 15;
    const int q  = l >> 4;

    const u16* A = out2p + (size_t)px0g * 256;

    f32x4 acc[4] = {{0.f,0.f,0.f,0.f},{0.f,0.f,0.f,0.f},
                    {0.f,0.f,0.f,0.f},{0.f,0.f,0.f,0.f}};
#pragma unroll
    for (int s = 0; s < 8; ++s) {
        bf16x8 bf = *(const bf16x8*)(bfr2 + ((size_t)(s * 4 + nt) * 64 + l) * 8);
#pragma unroll
        for (int mt = 0; mt < 4; ++mt) {
            const u16* ap = A + ((size_t)(mt * 16 + c)) * 256 + s * 32 + q * 8;
            bf16x8 a = *(const bf16x8*)ap;
            acc[mt] = __builtin_amdgcn_mfma_f32_16x16x32_bf16(a, bf, acc[mt], 0, 0, 0);
        }
    }
    const int co = nt * 16 + c;
    const float bias = ob[co];
    float* ob_ = out + (size_t)(n * OC + co) * HDWD + px0;
#pragma unroll
    for (int mt = 0; mt < 4; ++mt)
#pragma unroll
        for (int r = 0; r < 4; ++r)
            ob_[mt * 16 + q * 4 + r] = acc[mt][r] + bias;
}

extern "C" void kernel_launch(void* const* d_in, const int* in_sizes, int n_in,
                              void* d_out, int out_size, void* d_ws, size_t ws_size,
                              hipStream_t stream) {
    const float* x  = (const float*)d_in[0];
    const float* dw = (const float*)d_in[1];
    const float* db = (const float*)d_in[2];
    const float* ew = (const float*)d_in[3];
    const float* eb = (const float*)d_in[4];
    const float* ow = (const float*)d_in[5];
    const float* ob = (const float*)d_in[6];
    float* out = (float*)d_out;

    char* ws = (char*)d_ws;
    u16*   k1    = (u16*)ws;                              // [n][px][cm] 16.8 MB
    float* ksm   = (float*)(ws + 16777216);               // 3.3 MB
    u16*   out2p = (u16*)(ws + 16777216 + 3276800);       // [n][px][c2] 16.8 MB
    u16*   bfr   = out2p;          // 36 KB: kW2 writes, kB2 reads, kC2 clobbers
    u16*   bfr2  = k1;             // 32 KB: kW3 writes AFTER kB2 (k1 dead), kD2 reads

    kW2_pack<<<dim3(9),    dim3(256), 0, stream>>>(ew, bfr);
    kA_down <<<dim3(1024), dim3(256), 0, stream>>>(x, dw, db, k1);
    kB2_enc <<<dim3(512),  dim3(256), 0, stream>>>(k1, bfr, eb, ksm);
    kW3_pack<<<dim3(8),    dim3(256), 0, stream>>>(ow, bfr2);
    kC2_reassemble<<<dim3(1024), dim3(256), 0, stream>>>(x, ksm, out2p);
    kD2_out <<<dim3(512),  dim3(256), 0, stream>>>(out2p, bfr2, ob, out);
}

// Round 11
// 168.793 us; speedup vs baseline: 1.0703x; 1.0703x over previous
//
#include <hip/hip_runtime.h>
#include <hip/hip_bf16.h>

using u16 = unsigned short;
typedef __attribute__((ext_vector_type(8))) short bf16x8;
typedef __attribute__((ext_vector_type(4))) float f32x4;

static constexpr int N  = 2;
static constexpr int C  = 64;
static constexpr int H  = 256;
static constexpr int W  = 256;
static constexpr int Hd = 128;
static constexpr int Wd = 128;
static constexpr int KK = 25;
static constexpr int C2 = 256;
static constexpr int OC = 64;
static constexpr int HWP  = H * W;    // 65536
static constexpr int HDWD = Hd * Wd;  // 16384

__device__ __forceinline__ float bflo(unsigned u) { return __uint_as_float(u << 16); }
__device__ __forceinline__ float bfhi(unsigned u) { return __uint_as_float(u & 0xffff0000u); }
__device__ __forceinline__ unsigned pack2(float a, float b) {
    __hip_bfloat16 ha = __float2bfloat16(a), hb = __float2bfloat16(b);
    union { __hip_bfloat16 h; u16 u; } ua{ha}, ub{hb};
    return (unsigned)ua.u | ((unsigned)ub.u << 16);
}
__device__ __forceinline__ u16 f2bf(float f) {
    union { __hip_bfloat16 h; u16 u; } v{__float2bfloat16(f)};
    return v.u;
}

// ---------------- Kernel A: 1x1 down conv -> k1 PIXEL-MAJOR [n][px][cm] -----
__global__ __launch_bounds__(256) void kA_down(const float* __restrict__ x,
                                               const float* __restrict__ w,
                                               const float* __restrict__ b,
                                               u16* __restrict__ k1) {
    __shared__ u16   xt[64][128];
    __shared__ float wt[64][66];
    const int tid = threadIdx.x;
    const int pg0 = blockIdx.x * 128;
    const int n   = pg0 >> 16;
    const int px0 = pg0 & (HWP - 1);

#pragma unroll
    for (int i = 0; i < 16; ++i) {
        int e  = i * 256 + tid;
        int cm = e >> 6, c = e & 63;
        wt[c][cm] = w[e];
    }
    const float* xb = x + (size_t)n * C * HWP + px0;
#pragma unroll
    for (int i = 0; i < 8; ++i) {
        int flat = i * 256 + tid;
        int row  = flat >> 5;
        int col4 = flat & 31;
        float4 v = *(const float4*)(xb + (size_t)row * HWP + col4 * 4);
        uint2 p;
        p.x = pack2(v.x, v.y);
        p.y = pack2(v.z, v.w);
        *(uint2*)&xt[row][col4 * 4] = p;
    }
    __syncthreads();

    const int cg  = tid & 7;
    const int pxg = tid >> 3;
    float acc[8][4];
#pragma unroll
    for (int j = 0; j < 8; ++j) {
        float bj = b[cg * 8 + j];
#pragma unroll
        for (int p = 0; p < 4; ++p) acc[j][p] = bj;
    }
#pragma unroll 8
    for (int c = 0; c < 64; ++c) {
        uint2 xv = *(const uint2*)&xt[c][pxg * 4];
        float xs[4] = {bflo(xv.x), bfhi(xv.x), bflo(xv.y), bfhi(xv.y)};
        float2 w01 = *(const float2*)&wt[c][cg * 8 + 0];
        float2 w23 = *(const float2*)&wt[c][cg * 8 + 2];
        float2 w45 = *(const float2*)&wt[c][cg * 8 + 4];
        float2 w67 = *(const float2*)&wt[c][cg * 8 + 6];
        float wv[8] = {w01.x, w01.y, w23.x, w23.y, w45.x, w45.y, w67.x, w67.y};
#pragma unroll
        for (int j = 0; j < 8; ++j)
#pragma unroll
            for (int p = 0; p < 4; ++p) acc[j][p] = fmaf(wv[j], xs[p], acc[j][p]);
    }
#pragma unroll
    for (int p = 0; p < 4; ++p) {
        uint4 o;
        o.x = pack2(acc[0][p], acc[1][p]);
        o.y = pack2(acc[2][p], acc[3][p]);
        o.z = pack2(acc[4][p], acc[5][p]);
        o.w = pack2(acc[6][p], acc[7][p]);
        *(uint4*)(k1 + ((size_t)pg0 + pxg * 4 + p) * 64 + cg * 8) = o;
    }
}

// ---- Kernel W: pack enc + out weights into MFMA B-fragment layouts ---------
__global__ __launch_bounds__(256) void kW_pack(const float* __restrict__ ew,
                                               const float* __restrict__ ow,
                                               u16* __restrict__ bfr,
                                               u16* __restrict__ bfr2) {
    int idx = blockIdx.x * 256 + threadIdx.x;   // 0..4607
    if (idx < 2304) {
        int l  = idx & 63;
        int ft = idx >> 6;
        int t  = ft & 1, s = ft >> 1;
        int tap = s >> 1, h = s & 1;
        int c = l & 15, q = l >> 4;
        int kk = t * 16 + c;
        u16 o[8];
#pragma unroll
        for (int j = 0; j < 8; ++j) {
            int cm = 32 * h + 8 * q + j;
            float v = (kk < 25) ? ew[(kk * 64 + cm) * 9 + tap] : 0.f;
            o[j] = f2bf(v);
        }
        *(uint4*)(bfr + (size_t)idx * 8) = *(uint4*)o;
    } else if (idx < 4352) {
        int i2 = idx - 2304;
        int l  = i2 & 63;
        int ft = i2 >> 6;
        int nt = ft & 3, s = ft >> 2;
        int c = l & 15, q = l >> 4;
        int co = nt * 16 + c;
        u16 o[8];
#pragma unroll
        for (int j = 0; j < 8; ++j)
            o[j] = f2bf(ow[co * 256 + s * 32 + q * 8 + j]);
        *(uint4*)(bfr2 + (size_t)i2 * 8) = *(uint4*)o;
    }
}

// -------- Kernel B2: enc conv as MFMA GEMM + in-register softmax ------------
__global__ __launch_bounds__(256) void kB2_enc(const u16* __restrict__ k1,
                                               const u16* __restrict__ bfr,
                                               const float* __restrict__ eb,
                                               float* __restrict__ ksm) {
    __shared__ u16 tile[3 * 130 * 72];
    const int tid = threadIdx.x;
    const int b   = blockIdx.x;
    const int half = b & 1;
    const int hd   = (b >> 1) & 127;
    const int n    = b >> 8;
    const int w0 = half * 64;
    const int xb = 2 * w0 - 1;
    const int y0 = 2 * hd - 1;
    const u16* kb = k1 + (size_t)n * HWP * 64;

    for (int r = 0; r < 13; ++r) {
        int f = r * 256 + tid;
        if (f < 3096) {
            int p  = f >> 3, ch = f & 7;
            int y  = p / 129, xi = p - y * 129;
            int yy = y0 + y, xx = xb + xi;
            uint4 v = make_uint4(0u, 0u, 0u, 0u);
            if (yy >= 0 && xx >= 0 && xx < 256)
                v = *(const uint4*)(kb + ((size_t)(yy * W + xx)) * 64 + ch * 8);
            *(uint4*)&tile[(y * 130 + xi) * 72 + ch * 8] = v;
        }
    }
    __syncthreads();

    const int wv = tid >> 6;
    const int l  = tid & 63;
    const int c  = l & 15;
    const int q  = l >> 4;

    f32x4 acc0 = {0.f, 0.f, 0.f, 0.f};
    f32x4 acc1 = {0.f, 0.f, 0.f, 0.f};
#pragma unroll
    for (int s = 0; s < 18; ++s) {
        const int tap = s >> 1, h = s & 1;
        const int dy = tap / 3, dx = tap - dy * 3;
        const u16* ap = &tile[(dy * 130 + 32 * wv + 2 * c + dx) * 72 + 32 * h + 8 * q];
        bf16x8 a  = *(const bf16x8*)ap;
        bf16x8 b0 = *(const bf16x8*)(bfr + ((size_t)(s * 2 + 0) * 64 + l) * 8);
        bf16x8 b1 = *(const bf16x8*)(bfr + ((size_t)(s * 2 + 1) * 64 + l) * 8);
        acc0 = __builtin_amdgcn_mfma_f32_16x16x32_bf16(a, b0, acc0, 0, 0, 0);
        acc1 = __builtin_amdgcn_mfma_f32_16x16x32_bf16(a, b1, acc1, 0, 0, 0);
    }

    const float e0 = eb[c];
    const float e1 = eb[min(16 + c, 24)];
    const bool c9 = (c < 9);

#pragma unroll
    for (int r = 0; r < 4; ++r) {
        float l0 = acc0[r] + e0;
        float l1 = c9 ? (acc1[r] + e1) : -1e30f;
        float mx = fmaxf(l0, l1);
#pragma unroll
        for (int d = 1; d < 16; d <<= 1) mx = fmaxf(mx, __shfl_xor(mx, d, 64));
        float x0 = __expf(l0 - mx);
        float x1 = c9 ? __expf(l1 - mx) : 0.f;
        float sm = x0 + x1;
#pragma unroll
        for (int d = 1; d < 16; d <<= 1) sm += __shfl_xor(sm, d, 64);
        float inv = 1.f / sm;
        int wd = w0 + 16 * wv + q * 4 + r;
        float* op = ksm + (size_t)n * KK * HDWD + hd * Wd + wd;
        op[(size_t)c * HDWD] = x0 * inv;
        if (c9) op[(size_t)(16 + c) * HDWD] = x1 * inv;
    }
}

// ---- Kernel C3: reassembly -> out2 PIXEL-MAJOR [n][px][c2] -----------------
// Same decomposition as kC2 but register-dieted: ci loop NOT unrolled, per-ci
// immediate uint2 stores (4 consecutive c2 = q0..q3). L2 merges the scatter
// (evidence: R10 WRITE_SIZE == ideal).
__global__ __launch_bounds__(256) void kC3_reassemble(const float* __restrict__ x,
                                                      const float* __restrict__ ksm,
                                                      u16* __restrict__ out2p) {
    __shared__ float xts[4 * 6 * 272];   // 4 q-strips x 6 rows x 272 floats
    const int tid = threadIdx.x;
    const int b   = blockIdx.x;
    const int cc  = b & 15;
    const int hdt = (b >> 4) & 31;
    const int n   = b >> 9;
    const int hd0 = hdt * 4;
    const int hdo = tid >> 6;        // 0..3
    const int wdg = tid & 63;        // 0..63
    const int hd  = hd0 + hdo;
    const int wd0 = wdg * 2;
    const int w0  = ((hdo & 1) << 7) + wd0;
    const int lr0 = hdo >> 1;
    const int c0  = cc * 4;

    // softmax weights once (shared by all q and all ci)
    const float* kb = ksm + (size_t)n * KK * HDWD + hd * Wd + wd0;
    float2 kw[25];
#pragma unroll
    for (int kk = 0; kk < 25; ++kk) kw[kk] = *(const float2*)(kb + (size_t)kk * HDWD);

    // staging descriptors: 1632 float4 slots = 4 strips x 6 rows x 68 slots
    int  soff[7];
    bool sval[7];
#pragma unroll
    for (int k = 0; k < 7; ++k) {
        int s = tid + 256 * k;
        int strip = s / 408;
        int rem   = s - 408 * strip;
        int r     = rem / 68;
        int c4    = rem - 68 * r;
        int y     = strip * 64 + (hd0 >> 1) - 2 + r;
        sval[k] = (s < 1632) & (c4 >= 1) & (c4 <= 64) & (y >= 0) & (y < H);
        int yc  = min(max(y, 0), H - 1);
        soff[k] = yc * W + (c4 - 1) * 4;
    }

    const float4 z = make_float4(0.f, 0.f, 0.f, 0.f);
    u16* const pbase = out2p + ((size_t)(n * HDWD + hd * Wd + wd0)) * 256;

#pragma unroll 1
    for (int ci = 0; ci < 4; ++ci) {
        __syncthreads();
        const float* base = x + (size_t)(n * C + c0 + ci) * HWP;
#pragma unroll
        for (int k = 0; k < 7; ++k) {
            int s = tid + 256 * k;
            if (s < 1632) {
                float4 v = sval[k] ? *(const float4*)(base + soff[k]) : z;
                *(float4*)&xts[4 * s] = v;
            }
        }
        __syncthreads();

        float a0[4], a1[4];
#pragma unroll
        for (int q = 0; q < 4; ++q) {
            float s0 = 0.f, s1 = 0.f;
#pragma unroll
            for (int i = 0; i < 5; ++i) {
                const float* rr = &xts[(q * 6 + lr0 + i) * 272 + w0 + 2];
                float2 r0 = *(const float2*)(rr + 0);
                float2 r1 = *(const float2*)(rr + 2);
                float2 r2 = *(const float2*)(rr + 4);
                float f[6] = {r0.x, r0.y, r1.x, r1.y, r2.x, r2.y};
#pragma unroll
                for (int j = 0; j < 5; ++j) {
                    const float2 kv = kw[i * 5 + j];
                    s0 = fmaf(f[j + 0], kv.x, s0);
                    s1 = fmaf(f[j + 1], kv.y, s1);
                }
            }
            a0[q] = s0; a1[q] = s1;
        }
        // c2 = 4*(c0+ci) + q, q=0..3 contiguous -> 8B per px
        const int c2o = (c0 + ci) * 4;
        *(uint2*)(pbase + c2o)       = make_uint2(pack2(a0[0], a0[1]), pack2(a0[2], a0[3]));
        *(uint2*)(pbase + 256 + c2o) = make_uint2(pack2(a1[0], a1[1]), pack2(a1[2], a1[3]));
    }
}

// ---- Kernel D2: 1x1 out conv as MFMA GEMM (no LDS) -------------------------
__global__ __launch_bounds__(256) void kD2_out(const u16* __restrict__ out2p,
                                               const u16* __restrict__ bfr2,
                                               const float* __restrict__ ob,
                                               float* __restrict__ out) {
    const int tid = threadIdx.x;
    const int b   = blockIdx.x;
    const int px0g = b * 64;
    const int n    = px0g >> 14;
    const int px0  = px0g & (HDWD - 1);
    const int nt = tid >> 6;
    const int l  = tid & 63;
    const int c  = l & 15;
    const int q  = l >> 4;

    const u16* A = out2p + (size_t)px0g * 256;

    f32x4 acc[4] = {{0.f,0.f,0.f,0.f},{0.f,0.f,0.f,0.f},
                    {0.f,0.f,0.f,0.f},{0.f,0.f,0.f,0.f}};
#pragma unroll
    for (int s = 0; s < 8; ++s) {
        bf16x8 bf = *(const bf16x8*)(bfr2 + ((size_t)(s * 4 + nt) * 64 + l) * 8);
#pragma unroll
        for (int mt = 0; mt < 4; ++mt) {
            const u16* ap = A + ((size_t)(mt * 16 + c)) * 256 + s * 32 + q * 8;
            bf16x8 a = *(const bf16x8*)ap;
            acc[mt] = __builtin_amdgcn_mfma_f32_16x16x32_bf16(a, bf, acc[mt], 0, 0, 0);
        }
    }
    const int co = nt * 16 + c;
    const float bias = ob[co];
    float* ob_ = out + (size_t)(n * OC + co) * HDWD + px0;
#pragma unroll
    for (int mt = 0; mt < 4; ++mt)
#pragma unroll
        for (int r = 0; r < 4; ++r)
            ob_[mt * 16 + q * 4 + r] = acc[mt][r] + bias;
}

extern "C" void kernel_launch(void* const* d_in, const int* in_sizes, int n_in,
                              void* d_out, int out_size, void* d_ws, size_t ws_size,
                              hipStream_t stream) {
    const float* x  = (const float*)d_in[0];
    const float* dw = (const float*)d_in[1];
    const float* db = (const float*)d_in[2];
    const float* ew = (const float*)d_in[3];
    const float* eb = (const float*)d_in[4];
    const float* ow = (const float*)d_in[5];
    const float* ob = (const float*)d_in[6];
    float* out = (float*)d_out;

    char* ws = (char*)d_ws;
    u16*   k1    = (u16*)ws;                              // [n][px][cm] 16.8 MB
    float* ksm   = (float*)(ws + 16777216);               // 3.3 MB
    u16*   out2p = (u16*)(ws + 16777216 + 3276800);       // [n][px][c2] 16.8 MB
    u16*   bfr   = out2p;          // 36 KB: kW writes, kB2 reads, kC3 clobbers
    u16*   bfr2  = (u16*)(ws + 16777216 + 3276800 + 16777216); // 32 KB own slot

    kW_pack <<<dim3(18),   dim3(256), 0, stream>>>(ew, ow, bfr, bfr2);
    kA_down <<<dim3(1024), dim3(256), 0, stream>>>(x, dw, db, k1);
    kB2_enc <<<dim3(512),  dim3(256), 0, stream>>>(k1, bfr, eb, ksm);
    kC3_reassemble<<<dim3(1024), dim3(256), 0, stream>>>(x, ksm, out2p);
    kD2_out <<<dim3(512),  dim3(256), 0, stream>>>(out2p, bfr2, ob, out);
}

// Round 12
// 162.449 us; speedup vs baseline: 1.1121x; 1.0391x over previous
//
#include <hip/hip_runtime.h>
#include <hip/hip_bf16.h>

using u16 = unsigned short;
typedef __attribute__((ext_vector_type(8))) short bf16x8;
typedef __attribute__((ext_vector_type(4))) float f32x4;

static constexpr int N  = 2;
static constexpr int C  = 64;
static constexpr int H  = 256;
static constexpr int W  = 256;
static constexpr int Hd = 128;
static constexpr int Wd = 128;
static constexpr int KK = 25;
static constexpr int C2 = 256;
static constexpr int OC = 64;
static constexpr int HWP  = H * W;    // 65536
static constexpr int HDWD = Hd * Wd;  // 16384

__device__ __forceinline__ float bflo(unsigned u) { return __uint_as_float(u << 16); }
__device__ __forceinline__ float bfhi(unsigned u) { return __uint_as_float(u & 0xffff0000u); }
__device__ __forceinline__ unsigned pack2(float a, float b) {
    __hip_bfloat16 ha = __float2bfloat16(a), hb = __float2bfloat16(b);
    union { __hip_bfloat16 h; u16 u; } ua{ha}, ub{hb};
    return (unsigned)ua.u | ((unsigned)ub.u << 16);
}
__device__ __forceinline__ u16 f2bf(float f) {
    union { __hip_bfloat16 h; u16 u; } v{__float2bfloat16(f)};
    return v.u;
}

// ---------------- Kernel A: 1x1 down conv -> k1 PIXEL-MAJOR [n][px][cm] -----
__global__ __launch_bounds__(256) void kA_down(const float* __restrict__ x,
                                               const float* __restrict__ w,
                                               const float* __restrict__ b,
                                               u16* __restrict__ k1) {
    __shared__ u16   xt[64][128];
    __shared__ float wt[64][66];
    const int tid = threadIdx.x;
    const int pg0 = blockIdx.x * 128;
    const int n   = pg0 >> 16;
    const int px0 = pg0 & (HWP - 1);

#pragma unroll
    for (int i = 0; i < 16; ++i) {
        int e  = i * 256 + tid;
        int cm = e >> 6, c = e & 63;
        wt[c][cm] = w[e];
    }
    const float* xb = x + (size_t)n * C * HWP + px0;
#pragma unroll
    for (int i = 0; i < 8; ++i) {
        int flat = i * 256 + tid;
        int row  = flat >> 5;
        int col4 = flat & 31;
        float4 v = *(const float4*)(xb + (size_t)row * HWP + col4 * 4);
        uint2 p;
        p.x = pack2(v.x, v.y);
        p.y = pack2(v.z, v.w);
        *(uint2*)&xt[row][col4 * 4] = p;
    }
    __syncthreads();

    const int cg  = tid & 7;
    const int pxg = tid >> 3;
    float acc[8][4];
#pragma unroll
    for (int j = 0; j < 8; ++j) {
        float bj = b[cg * 8 + j];
#pragma unroll
        for (int p = 0; p < 4; ++p) acc[j][p] = bj;
    }
#pragma unroll 8
    for (int c = 0; c < 64; ++c) {
        uint2 xv = *(const uint2*)&xt[c][pxg * 4];
        float xs[4] = {bflo(xv.x), bfhi(xv.x), bflo(xv.y), bfhi(xv.y)};
        float2 w01 = *(const float2*)&wt[c][cg * 8 + 0];
        float2 w23 = *(const float2*)&wt[c][cg * 8 + 2];
        float2 w45 = *(const float2*)&wt[c][cg * 8 + 4];
        float2 w67 = *(const float2*)&wt[c][cg * 8 + 6];
        float wv[8] = {w01.x, w01.y, w23.x, w23.y, w45.x, w45.y, w67.x, w67.y};
#pragma unroll
        for (int j = 0; j < 8; ++j)
#pragma unroll
            for (int p = 0; p < 4; ++p) acc[j][p] = fmaf(wv[j], xs[p], acc[j][p]);
    }
#pragma unroll
    for (int p = 0; p < 4; ++p) {
        uint4 o;
        o.x = pack2(acc[0][p], acc[1][p]);
        o.y = pack2(acc[2][p], acc[3][p]);
        o.z = pack2(acc[4][p], acc[5][p]);
        o.w = pack2(acc[6][p], acc[7][p]);
        *(uint4*)(k1 + ((size_t)pg0 + pxg * 4 + p) * 64 + cg * 8) = o;
    }
}

// ---- Kernel W: pack enc + out weights into MFMA B-fragment layouts ---------
__global__ __launch_bounds__(256) void kW_pack(const float* __restrict__ ew,
                                               const float* __restrict__ ow,
                                               u16* __restrict__ bfr,
                                               u16* __restrict__ bfr2) {
    int idx = blockIdx.x * 256 + threadIdx.x;   // 0..4607
    if (idx < 2304) {
        int l  = idx & 63;
        int ft = idx >> 6;
        int t  = ft & 1, s = ft >> 1;
        int tap = s >> 1, h = s & 1;
        int c = l & 15, q = l >> 4;
        int kk = t * 16 + c;
        u16 o[8];
#pragma unroll
        for (int j = 0; j < 8; ++j) {
            int cm = 32 * h + 8 * q + j;
            float v = (kk < 25) ? ew[(kk * 64 + cm) * 9 + tap] : 0.f;
            o[j] = f2bf(v);
        }
        *(uint4*)(bfr + (size_t)idx * 8) = *(uint4*)o;
    } else if (idx < 4352) {
        int i2 = idx - 2304;
        int l  = i2 & 63;
        int ft = i2 >> 6;
        int nt = ft & 3, s = ft >> 2;
        int c = l & 15, q = l >> 4;
        int co = nt * 16 + c;
        u16 o[8];
#pragma unroll
        for (int j = 0; j < 8; ++j)
            o[j] = f2bf(ow[co * 256 + s * 32 + q * 8 + j]);
        *(uint4*)(bfr2 + (size_t)i2 * 8) = *(uint4*)o;
    }
}

// -------- Kernel B2: enc conv as MFMA GEMM + in-register softmax ------------
__global__ __launch_bounds__(256) void kB2_enc(const u16* __restrict__ k1,
                                               const u16* __restrict__ bfr,
                                               const float* __restrict__ eb,
                                               float* __restrict__ ksm) {
    __shared__ u16 tile[3 * 130 * 72];
    const int tid = threadIdx.x;
    const int b   = blockIdx.x;
    const int half = b & 1;
    const int hd   = (b >> 1) & 127;
    const int n    = b >> 8;
    const int w0 = half * 64;
    const int xb = 2 * w0 - 1;
    const int y0 = 2 * hd - 1;
    const u16* kb = k1 + (size_t)n * HWP * 64;

    for (int r = 0; r < 13; ++r) {
        int f = r * 256 + tid;
        if (f < 3096) {
            int p  = f >> 3, ch = f & 7;
            int y  = p / 129, xi = p - y * 129;
            int yy = y0 + y, xx = xb + xi;
            uint4 v = make_uint4(0u, 0u, 0u, 0u);
            if (yy >= 0 && xx >= 0 && xx < 256)
                v = *(const uint4*)(kb + ((size_t)(yy * W + xx)) * 64 + ch * 8);
            *(uint4*)&tile[(y * 130 + xi) * 72 + ch * 8] = v;
        }
    }
    __syncthreads();

    const int wv = tid >> 6;
    const int l  = tid & 63;
    const int c  = l & 15;
    const int q  = l >> 4;

    f32x4 acc0 = {0.f, 0.f, 0.f, 0.f};
    f32x4 acc1 = {0.f, 0.f, 0.f, 0.f};
#pragma unroll
    for (int s = 0; s < 18; ++s) {
        const int tap = s >> 1, h = s & 1;
        const int dy = tap / 3, dx = tap - dy * 3;
        const u16* ap = &tile[(dy * 130 + 32 * wv + 2 * c + dx) * 72 + 32 * h + 8 * q];
        bf16x8 a  = *(const bf16x8*)ap;
        bf16x8 b0 = *(const bf16x8*)(bfr + ((size_t)(s * 2 + 0) * 64 + l) * 8);
        bf16x8 b1 = *(const bf16x8*)(bfr + ((size_t)(s * 2 + 1) * 64 + l) * 8);
        acc0 = __builtin_amdgcn_mfma_f32_16x16x32_bf16(a, b0, acc0, 0, 0, 0);
        acc1 = __builtin_amdgcn_mfma_f32_16x16x32_bf16(a, b1, acc1, 0, 0, 0);
    }

    const float e0 = eb[c];
    const float e1 = eb[min(16 + c, 24)];
    const bool c9 = (c < 9);

#pragma unroll
    for (int r = 0; r < 4; ++r) {
        float l0 = acc0[r] + e0;
        float l1 = c9 ? (acc1[r] + e1) : -1e30f;
        float mx = fmaxf(l0, l1);
#pragma unroll
        for (int d = 1; d < 16; d <<= 1) mx = fmaxf(mx, __shfl_xor(mx, d, 64));
        float x0 = __expf(l0 - mx);
        float x1 = c9 ? __expf(l1 - mx) : 0.f;
        float sm = x0 + x1;
#pragma unroll
        for (int d = 1; d < 16; d <<= 1) sm += __shfl_xor(sm, d, 64);
        float inv = 1.f / sm;
        int wd = w0 + 16 * wv + q * 4 + r;
        float* op = ksm + (size_t)n * KK * HDWD + hd * Wd + wd;
        op[(size_t)c * HDWD] = x0 * inv;
        if (c9) op[(size_t)(16 + c) * HDWD] = x1 * inv;
    }
}

// ---- Kernel C4: reassembly -> out2 PIXEL-MAJOR [n][px][c2] -----------------
// kC3 register-lean loop + LDS output buffer so final global stores are
// 32B-contiguous per px (R10-style, which merged: WRITE_SIZE ~= ideal).
__global__ __launch_bounds__(256) void kC4_reassemble(const float* __restrict__ x,
                                                      const float* __restrict__ ksm,
                                                      u16* __restrict__ out2p) {
    __shared__ float xts[4 * 6 * 272];   // 26112 B
    __shared__ u16   obuf[512][24];      // 24576 B: 512 px x 16 c2 (pad 24)
    const int tid = threadIdx.x;
    const int b   = blockIdx.x;
    const int cc  = b & 15;
    const int hdt = (b >> 4) & 31;
    const int n   = b >> 9;
    const int hd0 = hdt * 4;
    const int hdo = tid >> 6;        // 0..3
    const int wdg = tid & 63;        // 0..63
    const int hd  = hd0 + hdo;
    const int wd0 = wdg * 2;
    const int w0  = ((hdo & 1) << 7) + wd0;
    const int lr0 = hdo >> 1;
    const int c0  = cc * 4;
    const int p0  = hdo * 128 + wd0;   // px_local (even)

    // softmax weights once (shared by all q and all ci)
    const float* kb = ksm + (size_t)n * KK * HDWD + hd * Wd + wd0;
    float2 kw[25];
#pragma unroll
    for (int kk = 0; kk < 25; ++kk) kw[kk] = *(const float2*)(kb + (size_t)kk * HDWD);

    // staging descriptors: 1632 float4 slots = 4 strips x 6 rows x 68 slots
    int  soff[7];
    bool sval[7];
#pragma unroll
    for (int k = 0; k < 7; ++k) {
        int s = tid + 256 * k;
        int strip = s / 408;
        int rem   = s - 408 * strip;
        int r     = rem / 68;
        int c4    = rem - 68 * r;
        int y     = strip * 64 + (hd0 >> 1) - 2 + r;
        sval[k] = (s < 1632) & (c4 >= 1) & (c4 <= 64) & (y >= 0) & (y < H);
        int yc  = min(max(y, 0), H - 1);
        soff[k] = yc * W + (c4 - 1) * 4;
    }

    const float4 z = make_float4(0.f, 0.f, 0.f, 0.f);

#pragma unroll 1
    for (int ci = 0; ci < 4; ++ci) {
        __syncthreads();
        const float* base = x + (size_t)(n * C + c0 + ci) * HWP;
#pragma unroll
        for (int k = 0; k < 7; ++k) {
            int s = tid + 256 * k;
            if (s < 1632) {
                float4 v = sval[k] ? *(const float4*)(base + soff[k]) : z;
                *(float4*)&xts[4 * s] = v;
            }
        }
        __syncthreads();

        float a0[4], a1[4];
#pragma unroll
        for (int q = 0; q < 4; ++q) {
            float s0 = 0.f, s1 = 0.f;
#pragma unroll
            for (int i = 0; i < 5; ++i) {
                const float* rr = &xts[(q * 6 + lr0 + i) * 272 + w0 + 2];
                float2 r0 = *(const float2*)(rr + 0);
                float2 r1 = *(const float2*)(rr + 2);
                float2 r2 = *(const float2*)(rr + 4);
                float f[6] = {r0.x, r0.y, r1.x, r1.y, r2.x, r2.y};
#pragma unroll
                for (int j = 0; j < 5; ++j) {
                    const float2 kv = kw[i * 5 + j];
                    s0 = fmaf(f[j + 0], kv.x, s0);
                    s1 = fmaf(f[j + 1], kv.y, s1);
                }
            }
            a0[q] = s0; a1[q] = s1;
        }
        // park in LDS: 8B per px, word index ci*4..ci*4+3 (local c2)
        *(uint2*)&obuf[p0][ci * 4]     = make_uint2(pack2(a0[0], a0[1]), pack2(a0[2], a0[3]));
        *(uint2*)&obuf[p0 + 1][ci * 4] = make_uint2(pack2(a1[0], a1[1]), pack2(a1[2], a1[3]));
    }
    __syncthreads();

    // final: 32B contiguous per px (merges in L2 -> no partial-sector RMW)
    u16* dst = out2p + ((size_t)(n * HDWD + hd * Wd + wd0)) * 256 + cc * 16;
    uint4 wa = *(const uint4*)&obuf[p0][0];
    uint4 wb = *(const uint4*)&obuf[p0][8];
    *(uint4*)(dst + 0) = wa;
    *(uint4*)(dst + 8) = wb;
    uint4 wc = *(const uint4*)&obuf[p0 + 1][0];
    uint4 wd_ = *(const uint4*)&obuf[p0 + 1][8];
    *(uint4*)(dst + 256 + 0) = wc;
    *(uint4*)(dst + 256 + 8) = wd_;
}

// ---- Kernel D2: 1x1 out conv as MFMA GEMM (no LDS) -------------------------
__global__ __launch_bounds__(256) void kD2_out(const u16* __restrict__ out2p,
                                               const u16* __restrict__ bfr2,
                                               const float* __restrict__ ob,
                                               float* __restrict__ out) {
    const int tid = threadIdx.x;
    const int b   = blockIdx.x;
    const int px0g = b * 64;
    const int n    = px0g >> 14;
    const int px0  = px0g & (HDWD - 1);
    const int nt = tid >> 6;
    const int l  = tid & 63;
    const int c  = l & 15;
    const int q  = l >> 4;

    const u16* A = out2p + (size_t)px0g * 256;

    f32x4 acc[4] = {{0.f,0.f,0.f,0.f},{0.f,0.f,0.f,0.f},
                    {0.f,0.f,0.f,0.f},{0.f,0.f,0.f,0.f}};
#pragma unroll
    for (int s = 0; s < 8; ++s) {
        bf16x8 bf = *(const bf16x8*)(bfr2 + ((size_t)(s * 4 + nt) * 64 + l) * 8);
#pragma unroll
        for (int mt = 0; mt < 4; ++mt) {
            const u16* ap = A + ((size_t)(mt * 16 + c)) * 256 + s * 32 + q * 8;
            bf16x8 a = *(const bf16x8*)ap;
            acc[mt] = __builtin_amdgcn_mfma_f32_16x16x32_bf16(a, bf, acc[mt], 0, 0, 0);
        }
    }
    const int co = nt * 16 + c;
    const float bias = ob[co];
    float* ob_ = out + (size_t)(n * OC + co) * HDWD + px0;
#pragma unroll
    for (int mt = 0; mt < 4; ++mt)
#pragma unroll
        for (int r = 0; r < 4; ++r)
            ob_[mt * 16 + q * 4 + r] = acc[mt][r] + bias;
}

extern "C" void kernel_launch(void* const* d_in, const int* in_sizes, int n_in,
                              void* d_out, int out_size, void* d_ws, size_t ws_size,
                              hipStream_t stream) {
    const float* x  = (const float*)d_in[0];
    const float* dw = (const float*)d_in[1];
    const float* db = (const float*)d_in[2];
    const float* ew = (const float*)d_in[3];
    const float* eb = (const float*)d_in[4];
    const float* ow = (const float*)d_in[5];
    const float* ob = (const float*)d_in[6];
    float* out = (float*)d_out;

    char* ws = (char*)d_ws;
    u16*   k1    = (u16*)ws;                              // [n][px][cm] 16.8 MB
    float* ksm   = (float*)(ws + 16777216);               // 3.3 MB
    u16*   out2p = (u16*)(ws + 16777216 + 3276800);       // [n][px][c2] 16.8 MB
    u16*   bfr   = out2p;          // 36 KB: kW writes, kB2 reads, kC4 clobbers
    u16*   bfr2  = (u16*)(ws + 16777216 + 3276800 + 16777216); // 32 KB own slot

    kW_pack <<<dim3(18),   dim3(256), 0, stream>>>(ew, ow, bfr, bfr2);
    kA_down <<<dim3(1024), dim3(256), 0, stream>>>(x, dw, db, k1);
    kB2_enc <<<dim3(512),  dim3(256), 0, stream>>>(k1, bfr, eb, ksm);
    kC4_reassemble<<<dim3(1024), dim3(256), 0, stream>>>(x, ksm, out2p);
    kD2_out <<<dim3(512),  dim3(256), 0, stream>>>(out2p, bfr2, ob, out);
}